// Round 6
// baseline (650.476 us; speedup 1.0000x reference)
//
#include <hip/hip_runtime.h>

#define NT   512
#define IMPN (2048 * 512)
#define HROW 72                      // ushorts per h_lds seq-row (144 B): pad for bank spread

typedef __attribute__((ext_vector_type(8))) short short8v;
typedef __attribute__((ext_vector_type(4))) float f32x4;

union Frag { short8v v; unsigned short s[8]; };

__device__ __forceinline__ float fsig(float x) {
    return __builtin_amdgcn_rcpf(1.0f + __expf(-x));
}
__device__ __forceinline__ float ftanh(float x) {
    return 2.0f * __builtin_amdgcn_rcpf(1.0f + __expf(-2.0f * x)) - 1.0f;
}
// fp32 -> bf16 RNE (scalar, prologue only)
__device__ __forceinline__ unsigned short f2bf(float f) {
    unsigned u = __float_as_uint(f);
    unsigned r = u + 0x7FFFu + ((u >> 16) & 1u);
    return (unsigned short)(r >> 16);
}
__device__ __forceinline__ float bf2f(unsigned short s) {
    return __uint_as_float(((unsigned)s) << 16);
}
// packed RNE bf16 pair: lo16 = bf16(a), hi16 = bf16(b)
__device__ __forceinline__ unsigned cvt_pk_bf16(float a, float b) {
    unsigned r;
    asm("v_cvt_pk_bf16_f32 %0, %1, %2" : "=v"(r) : "v"(a), "v"(b));
    return r;
}

// 512 blocks x 256 threads, 2 blocks/CU. Blocks 0..255 fwd, 256..511 bwd;
// block = 8 seqs (MFMA rows 8..15 wasted: wave-granular issue means the
// per-wave cost is identical to a 16-seq block, but 2 independent blocks/CU
// overlap each other's LDS/trans/MFMA latency -> latency-bound fix).
// Wave w owns units u = 16w + (lane&15); gate rows {u, 64+u, 128+u} as register
// bf16 2-level (H/L) B-fragments. MFMA 16x16x32: D[seq][unit],
// seq=(lane>>4)*4+reg, col=lane&15. acc3 = xh (B = rW broadcast).
// 3-product scheme {HH, LH, HL}: per-product err ~3*2^-16, contractive GRU ->
// final err few e-4 (bf16 output floor 2^-9 dominates).
// dir=1 consumes time REVERSED; imp stored at scan index.
__global__ __launch_bounds__(256, 2) void brits_mfma(
    const float* __restrict__ input,
    const float* __restrict__ gW_f, const float* __restrict__ gb_f,
    const float* __restrict__ rW_f, const float* __restrict__ rb_f,
    const float* __restrict__ fcW_f, const float* __restrict__ fcb_f,
    const float* __restrict__ Wih_f, const float* __restrict__ bih_f,
    const float* __restrict__ Whh_f, const float* __restrict__ bhh_f,
    const float* __restrict__ gW_b, const float* __restrict__ gb_b,
    const float* __restrict__ rW_b, const float* __restrict__ rb_b,
    const float* __restrict__ fcW_b, const float* __restrict__ fcb_b,
    const float* __restrict__ Wih_b, const float* __restrict__ bih_b,
    const float* __restrict__ Whh_b, const float* __restrict__ bhh_b,
    float* __restrict__ out, float* __restrict__ ws)
{
    __shared__ __align__(16) unsigned short h_lds[2][2][16 * HROW]; // [buf][lev][seq*HROW+unit]
    __shared__ __align__(16) float xmd_l[3 * 256];                  // [ch'][s*16+tau]
    __shared__ __align__(16) float impbuf[8][17];
    __shared__ __align__(16) float fcpart[16][4];

    const int tid  = threadIdx.x;
    const int w    = tid >> 6;
    const int lane = tid & 63;
    const int j    = lane & 15;
    const int g    = lane >> 4;
    const int u    = w * 16 + j;
    const int dir  = blockIdx.x >> 8;
    const int b0   = (blockIdx.x & 255) * 8;

    const float* gW  = dir ? gW_b  : gW_f;
    const float* gb  = dir ? gb_b  : gb_f;
    const float* rW  = dir ? rW_b  : rW_f;
    const float* rb  = dir ? rb_b  : rb_f;
    const float* fcW = dir ? fcW_b : fcW_f;
    const float* fcb = dir ? fcb_b : fcb_f;
    const float* Wih = dir ? Wih_b : Wih_f;
    const float* bih = dir ? bih_b : bih_f;
    const float* Whh = dir ? Whh_b : Whh_f;
    const float* bhh = dir ? bhh_b : bhh_f;

    // per-lane scalar constants
    const float gWu = gW[u], gbu = gb[u], fcWu = fcW[u];
    const int Rr = u, Rz = 64 + u, Rn = 128 + u;
    const float wxr = Wih[2 * Rr], wmr = Wih[2 * Rr + 1];
    const float wxz = Wih[2 * Rz], wmz = Wih[2 * Rz + 1];
    const float wxn = Wih[2 * Rn], wmn = Wih[2 * Rn + 1];
    const float br  = bih[Rr] + bhh[Rr];
    const float bz  = bih[Rz] + bhh[Rz];
    const float bin = bih[Rn], bhn = bhh[Rn];
    const float rb0 = rb[0];

    // B fragments: 4 targets (r,z,n,xh) x 2 k-tiles x 2 levels, registers.
    Frag B[4][2][2];
#pragma unroll
    for (int t = 0; t < 4; ++t) {
        const float* src = (t < 3) ? (Whh + (t * 64 + u) * 64) : rW;
#pragma unroll
        for (int kt = 0; kt < 2; ++kt) {
#pragma unroll
            for (int e = 0; e < 8; ++e) {
                const float v = src[kt * 32 + g * 8 + e];
                const unsigned short bH = f2bf(v);
                const unsigned short bL = f2bf(v - bf2f(bH));  // RNE residual
                B[t][kt][0].s[e] = bH;
                B[t][kt][1].s[e] = bL;
            }
        }
    }

    const float* inp = input + (size_t)b0 * 3072;
    float* impOut = out + 2048 + (size_t)dir * IMPN + (size_t)b0 * NT;

    float h[4] = {0.0f, 0.0f, 0.0f, 0.0f};

    for (int t = 0; t < NT; ++t) {
        const int tm = t & 15;
        if (tm == 0) {                            // 16-step chunk boundary
            __syncthreads();
            if (t > 0 && tid < 128) {             // coalesced imp flush (8 seqs)
                const int fs = tid >> 4, ft = tid & 15;
                impOut[fs * NT + (t - 16) + ft] = impbuf[fs][ft];
            }
            if (tid < 192) {                      // stage x/m/d chunk (scan order)
                const int s = tid / 12, r2 = tid - s * 12, c = r2 >> 2, grp = r2 & 3;
                const int ss = s & 7;             // replicate rows 8..15 (keep finite)
                const int cho = (c == 0) ? 0 : ((c == 1) ? 2 * NT : 3 * NT);
                const float* base = inp + (size_t)ss * 3072 + cho;
                float4 v;
                if (dir == 0) {
                    v = *(const float4*)(base + t + grp * 4);
                } else {
                    // scan tau = t+grp*4+e -> data time NT-1-tau; reversed load
                    float4 r = *(const float4*)(base + (NT - 4 - t - grp * 4));
                    v.x = r.w; v.y = r.z; v.z = r.y; v.w = r.x;
                }
                if (c == 0) {
                    v.x = (v.x != v.x) ? -1.0f : v.x;
                    v.y = (v.y != v.y) ? -1.0f : v.y;
                    v.z = (v.z != v.z) ? -1.0f : v.z;
                    v.w = (v.w != v.w) ? -1.0f : v.w;
                }
                *(float4*)&xmd_l[c * 256 + s * 16 + grp * 4] = v;
            }
            __syncthreads();
        }
        const int buf = t & 1;

        // ---- phase A: decay + packed H/L split + publish to LDS ----
        float dv[4];
#pragma unroll
        for (int q = 0; q < 4; ++q) dv[q] = xmd_l[512 + (4 * g + q) * 16 + tm];
#pragma unroll
        for (int q = 0; q < 4; ++q) h[q] *= fsig(dv[q] * gWu + gbu);
#pragma unroll
        for (int qp = 0; qp < 2; ++qp) {          // q pairs (0,1) and (2,3)
            const int q0 = 2 * qp, q1 = 2 * qp + 1;
            const unsigned pH = cvt_pk_bf16(h[q0], h[q1]);
            const float l0 = h[q0] - __uint_as_float(pH << 16);
            const float l1 = h[q1] - __uint_as_float(pH & 0xFFFF0000u);
            const unsigned pL = cvt_pk_bf16(l0, l1);
            const int s0 = (4 * g + q0) * HROW + u;
            const int s1 = (4 * g + q1) * HROW + u;
            h_lds[buf][0][s0] = (unsigned short)pH;
            h_lds[buf][0][s1] = (unsigned short)(pH >> 16);
            h_lds[buf][1][s0] = (unsigned short)pL;
            h_lds[buf][1][s1] = (unsigned short)(pL >> 16);
        }
        __syncthreads();

        // ---- phase B: A-frags + xv/mv prefetch + 24 MFMA (xh first, z last) ----
        Frag A[2][2];
#pragma unroll
        for (int kt = 0; kt < 2; ++kt)
#pragma unroll
            for (int lev = 0; lev < 2; ++lev)
                A[kt][lev].v = *(const short8v*)&h_lds[buf][lev][j * HROW + kt * 32 + 8 * g];

        float xvv[4], mvv[4];
#pragma unroll
        for (int q = 0; q < 4; ++q) {
            xvv[q] = xmd_l[(4 * g + q) * 16 + tm];
            mvv[q] = xmd_l[256 + (4 * g + q) * 16 + tm];
        }

        f32x4 acc0 = {0,0,0,0}, acc1 = {0,0,0,0}, acc2 = {0,0,0,0}, acc3 = {0,0,0,0};
#pragma unroll
        for (int kt = 0; kt < 2; ++kt) {
            acc3 = __builtin_amdgcn_mfma_f32_16x16x32_bf16(A[kt][0].v, B[3][kt][0].v, acc3, 0, 0, 0);
            acc0 = __builtin_amdgcn_mfma_f32_16x16x32_bf16(A[kt][0].v, B[0][kt][0].v, acc0, 0, 0, 0);
            acc2 = __builtin_amdgcn_mfma_f32_16x16x32_bf16(A[kt][0].v, B[2][kt][0].v, acc2, 0, 0, 0);
            acc1 = __builtin_amdgcn_mfma_f32_16x16x32_bf16(A[kt][0].v, B[1][kt][0].v, acc1, 0, 0, 0);
            acc3 = __builtin_amdgcn_mfma_f32_16x16x32_bf16(A[kt][1].v, B[3][kt][0].v, acc3, 0, 0, 0);
            acc0 = __builtin_amdgcn_mfma_f32_16x16x32_bf16(A[kt][1].v, B[0][kt][0].v, acc0, 0, 0, 0);
            acc2 = __builtin_amdgcn_mfma_f32_16x16x32_bf16(A[kt][1].v, B[2][kt][0].v, acc2, 0, 0, 0);
            acc1 = __builtin_amdgcn_mfma_f32_16x16x32_bf16(A[kt][1].v, B[1][kt][0].v, acc1, 0, 0, 0);
            acc3 = __builtin_amdgcn_mfma_f32_16x16x32_bf16(A[kt][0].v, B[3][kt][1].v, acc3, 0, 0, 0);
            acc0 = __builtin_amdgcn_mfma_f32_16x16x32_bf16(A[kt][0].v, B[0][kt][1].v, acc0, 0, 0, 0);
            acc2 = __builtin_amdgcn_mfma_f32_16x16x32_bf16(A[kt][0].v, B[2][kt][1].v, acc2, 0, 0, 0);
            acc1 = __builtin_amdgcn_mfma_f32_16x16x32_bf16(A[kt][0].v, B[1][kt][1].v, acc1, 0, 0, 0);
        }

        // ---- phase C: gates (in-register; an/bn precomputed off the r-chain) ----
#pragma unroll
        for (int q = 0; q < 4; ++q) {
            const int s = 4 * g + q;
            const float xv = xvv[q];
            const float mv = mvv[q];
            const float xh = acc3[q] + rb0;
            if (w == 0 && j == 0 && g < 2) impbuf[s][tm] = xh;
            const float xc = mv * xv + (1.0f - mv) * xh;
            const float an = wxn * xc + wmn * mv + bin;   // indep of rr
            const float bn = acc2[q] + bhn;               // indep of rr
            const float rr = fsig(acc0[q] + wxr * xc + wmr * mv + br);
            const float zz = fsig(acc1[q] + wxz * xc + wmz * mv + bz);
            const float nn = ftanh(an + rr * bn);
            h[q] = (1.0f - zz) * nn + zz * h[q];
        }
    }

    // epilogue: flush last imp chunk + fc reduction
    __syncthreads();
    if (tid < 128) {
        const int fs = tid >> 4, ft = tid & 15;
        impOut[fs * NT + (NT - 16) + ft] = impbuf[fs][ft];
    }
    float p2[4];
#pragma unroll
    for (int q = 0; q < 4; ++q) {
        p2[q] = h[q] * fcWu;
        p2[q] += __shfl_xor(p2[q], 1);
        p2[q] += __shfl_xor(p2[q], 2);
        p2[q] += __shfl_xor(p2[q], 4);
        p2[q] += __shfl_xor(p2[q], 8);
    }
    if (j == 0) {
#pragma unroll
        for (int q = 0; q < 4; ++q) fcpart[4 * g + q][w] = p2[q];
    }
    __syncthreads();
    if (tid < 8) {
        float4 xp = *(const float4*)&fcpart[tid][0];
        ws[dir * 2048 + b0 + tid] = xp.x + xp.y + xp.z + xp.w + fcb[0];
    }
}

__global__ void brits_combine(const float* __restrict__ ws, float* __restrict__ out)
{
    int i = blockIdx.x * 256 + threadIdx.x;
    if (i < 2048) out[i] = 0.5f * (ws[i] + ws[2048 + i]);
}

extern "C" void kernel_launch(void* const* d_in, const int* in_sizes, int n_in,
                              void* d_out, int out_size, void* d_ws, size_t ws_size,
                              hipStream_t stream)
{
    const float* p[21];
    for (int i = 0; i < 21; ++i) p[i] = (const float*)d_in[i];
    float* out = (float*)d_out;
    float* ws  = (float*)d_ws;   // 4096 floats used

    brits_mfma<<<512, 256, 0, stream>>>(
        p[0],
        p[1], p[2], p[3], p[4], p[5], p[6], p[7], p[8], p[9], p[10],
        p[11], p[12], p[13], p[14], p[15], p[16], p[17], p[18], p[19], p[20],
        out, ws);
    brits_combine<<<8, 256, 0, stream>>>(ws, out);
}

// Round 7
// 369.123 us; speedup vs baseline: 1.7622x; 1.7622x over previous
//
#include <hip/hip_runtime.h>

#define NT   512
#define IMPN (2048 * 512)
#define HROW 72                      // ushorts per h_lds seq-row (144 B): 2-way-free bank spread

typedef __attribute__((ext_vector_type(8))) short short8v;
typedef __attribute__((ext_vector_type(4))) float f32x4;

union Frag { short8v v; unsigned short s[8]; };

__device__ __forceinline__ float fsig(float x) {
    return __builtin_amdgcn_rcpf(1.0f + __expf(-x));
}
__device__ __forceinline__ float ftanh(float x) {
    return 2.0f * __builtin_amdgcn_rcpf(1.0f + __expf(-2.0f * x)) - 1.0f;
}
// fp32 -> bf16 RNE (scalar, prologue only)
__device__ __forceinline__ unsigned short f2bf(float f) {
    unsigned u = __float_as_uint(f);
    unsigned r = u + 0x7FFFu + ((u >> 16) & 1u);
    return (unsigned short)(r >> 16);
}
__device__ __forceinline__ float bf2f(unsigned short s) {
    return __uint_as_float(((unsigned)s) << 16);
}
// packed RNE bf16 pair: lo16 = bf16(a), hi16 = bf16(b)
__device__ __forceinline__ unsigned cvt_pk_bf16(float a, float b) {
    unsigned r;
    asm("v_cvt_pk_bf16_f32 %0, %1, %2" : "=v"(r) : "v"(a), "v"(b));
    return r;
}

// 256 blocks x 256 threads, 1 block/CU. Blocks 0..127 fwd, 128..255 bwd;
// block = 16 seqs. TRANSPOSED MFMA: weights are the A operand, h the B
// operand -> D[gate-row][seq]: lane (j,g) owns seq j and units 16w+4g+{0..3}.
// Fragments are bit-identical to the non-transposed scheme (A and B share the
// lane->(index,k) map); only arg order + per-lane ownership changed.
// Wave w computes gate rows {w,4+w,8+w}-th 16-row tiles = r/z/n for its units;
// acc3 = xh via rW broadcast rows (all D rows equal).
// 3-product split {W_H*h_H, W_H*h_L, W_L*h_H}: per-product err ~3*2^-16,
// contractive GRU -> final err few e-4 (output bf16 floor 2^-9 dominates).
// dir=1 consumes time REVERSED; imp stored at scan index.
__global__ __launch_bounds__(256, 1) void brits_mfma(
    const float* __restrict__ input,
    const float* __restrict__ gW_f, const float* __restrict__ gb_f,
    const float* __restrict__ rW_f, const float* __restrict__ rb_f,
    const float* __restrict__ fcW_f, const float* __restrict__ fcb_f,
    const float* __restrict__ Wih_f, const float* __restrict__ bih_f,
    const float* __restrict__ Whh_f, const float* __restrict__ bhh_f,
    const float* __restrict__ gW_b, const float* __restrict__ gb_b,
    const float* __restrict__ rW_b, const float* __restrict__ rb_b,
    const float* __restrict__ fcW_b, const float* __restrict__ fcb_b,
    const float* __restrict__ Wih_b, const float* __restrict__ bih_b,
    const float* __restrict__ Whh_b, const float* __restrict__ bhh_b,
    float* __restrict__ out, float* __restrict__ ws)
{
    __shared__ __align__(16) unsigned short h_lds[2][2][16 * HROW]; // [buf][lev][seq*HROW+unit]
    __shared__ __align__(16) float xmd_l[16][17][4];                // [seq][tau(+pad)][x,m,d,-]
    __shared__ __align__(16) float impbuf[16][17];
    __shared__ __align__(16) float fcpart[16][4];

    const int tid  = threadIdx.x;
    const int w    = tid >> 6;
    const int lane = tid & 63;
    const int j    = lane & 15;          // seq owned by this lane
    const int g    = lane >> 4;
    const int u    = w * 16 + j;         // weight-frag row unit
    const int u0   = w * 16 + 4 * g;     // first of this lane's 4 gate units
    const int dir  = blockIdx.x >> 7;
    const int b0   = (blockIdx.x & 127) * 16;

    const float* gW  = dir ? gW_b  : gW_f;
    const float* gb  = dir ? gb_b  : gb_f;
    const float* rW  = dir ? rW_b  : rW_f;
    const float* rb  = dir ? rb_b  : rb_f;
    const float* fcW = dir ? fcW_b : fcW_f;
    const float* fcb = dir ? fcb_b : fcb_f;
    const float* Wih = dir ? Wih_b : Wih_f;
    const float* bih = dir ? bih_b : bih_f;
    const float* Whh = dir ? Whh_b : Whh_f;
    const float* bhh = dir ? bhh_b : bhh_f;

    // per-lane per-q constants (units u0..u0+3)
    float gWq[4], gbq[4], fcq[4], wxr[4], wmr[4], wxz[4], wmz[4], wxn[4], wmn[4];
    float brq[4], bzq[4], binq[4], bhnq[4];
#pragma unroll
    for (int q = 0; q < 4; ++q) {
        const int uq = u0 + q;
        gWq[q] = gW[uq]; gbq[q] = gb[uq]; fcq[q] = fcW[uq];
        wxr[q] = Wih[2 * uq];         wmr[q] = Wih[2 * uq + 1];
        wxz[q] = Wih[2 * (64 + uq)];  wmz[q] = Wih[2 * (64 + uq) + 1];
        wxn[q] = Wih[2 * (128 + uq)]; wmn[q] = Wih[2 * (128 + uq) + 1];
        brq[q] = bih[uq] + bhh[uq];
        bzq[q] = bih[64 + uq] + bhh[64 + uq];
        binq[q] = bih[128 + uq]; bhnq[q] = bhh[128 + uq];
    }
    const float rb0 = rb[0];

    // weight A-fragments: 4 targets (r,z,n,xh) x 2 k-tiles x 2 levels.
    // lane (j,g): Wf[t<3] = Whh[t*64 + 16w + j][kt*32+8g+e]; Wf[3] = rW bcast.
    Frag Wf[4][2][2];
#pragma unroll
    for (int t = 0; t < 4; ++t) {
        const float* src = (t < 3) ? (Whh + (t * 64 + u) * 64) : rW;
#pragma unroll
        for (int kt = 0; kt < 2; ++kt) {
#pragma unroll
            for (int e = 0; e < 8; ++e) {
                const float v = src[kt * 32 + g * 8 + e];
                const unsigned short bH = f2bf(v);
                const unsigned short bL = f2bf(v - bf2f(bH));  // RNE residual
                Wf[t][kt][0].s[e] = bH;
                Wf[t][kt][1].s[e] = bL;
            }
        }
    }

    const float* inp = input + (size_t)b0 * 3072;
    float* impOut = out + 2048 + (size_t)dir * IMPN + (size_t)b0 * NT;

    float h[4] = {0.0f, 0.0f, 0.0f, 0.0f};   // units u0..u0+3, seq j

    for (int t = 0; t < NT; ++t) {
        const int tm = t & 15;
        if (tm == 0) {                            // 16-step chunk boundary
            __syncthreads();
            if (t > 0) {                          // coalesced imp flush
                const int fs = tid >> 4, ft = tid & 15;
                impOut[fs * NT + (t - 16) + ft] = impbuf[fs][ft];
            }
            {                                     // stage x/m/d chunk: thread=(s,tau)
                const int s = tid >> 4, tmi = tid & 15;
                const int tt = dir ? (NT - 1 - t - tmi) : (t + tmi);
                const float* base = inp + (size_t)s * 3072;
                float x = base[tt];
                x = (x != x) ? -1.0f : x;
                const float m  = base[2 * NT + tt];
                const float dd = base[3 * NT + tt];
                float4 v; v.x = x; v.y = m; v.z = dd; v.w = 0.0f;
                *(float4*)&xmd_l[s][tmi][0] = v;
            }
            __syncthreads();
        }
        const int buf = t & 1;

        // ---- phase A: read seq-j scalars, decay, pack H/L, publish (2x b64) ----
        const float4 xmd = *(const float4*)&xmd_l[j][tm][0];   // x, m, d
#pragma unroll
        for (int q = 0; q < 4; ++q) h[q] *= fsig(xmd.z * gWq[q] + gbq[q]);

        const unsigned pH0 = cvt_pk_bf16(h[0], h[1]);
        const unsigned pH1 = cvt_pk_bf16(h[2], h[3]);
        const float l0 = h[0] - __uint_as_float(pH0 << 16);
        const float l1 = h[1] - __uint_as_float(pH0 & 0xFFFF0000u);
        const float l2 = h[2] - __uint_as_float(pH1 << 16);
        const float l3 = h[3] - __uint_as_float(pH1 & 0xFFFF0000u);
        const unsigned pL0 = cvt_pk_bf16(l0, l1);
        const unsigned pL1 = cvt_pk_bf16(l2, l3);
        {
            const int off = j * HROW + u0;        // ushort index, 8B-aligned
            uint2 vH; vH.x = pH0; vH.y = pH1;
            uint2 vL; vL.x = pL0; vL.y = pL1;
            *(uint2*)&h_lds[buf][0][off] = vH;
            *(uint2*)&h_lds[buf][1][off] = vL;
        }
        __syncthreads();

        // ---- phase B: h B-frags (4x ds_read_b128) + 24 MFMA (xh first, z last) ----
        Frag A[2][2];
#pragma unroll
        for (int kt = 0; kt < 2; ++kt)
#pragma unroll
            for (int lev = 0; lev < 2; ++lev)
                A[kt][lev].v = *(const short8v*)&h_lds[buf][lev][j * HROW + kt * 32 + 8 * g];

        f32x4 acc0 = {0,0,0,0}, acc1 = {0,0,0,0}, acc2 = {0,0,0,0}, acc3 = {0,0,0,0};
#pragma unroll
        for (int kt = 0; kt < 2; ++kt) {
            // products (W_lev, h_lev): {(0,0), (0,1), (1,0)}; acc rotation 3,0,2,1
            acc3 = __builtin_amdgcn_mfma_f32_16x16x32_bf16(Wf[3][kt][0].v, A[kt][0].v, acc3, 0, 0, 0);
            acc0 = __builtin_amdgcn_mfma_f32_16x16x32_bf16(Wf[0][kt][0].v, A[kt][0].v, acc0, 0, 0, 0);
            acc2 = __builtin_amdgcn_mfma_f32_16x16x32_bf16(Wf[2][kt][0].v, A[kt][0].v, acc2, 0, 0, 0);
            acc1 = __builtin_amdgcn_mfma_f32_16x16x32_bf16(Wf[1][kt][0].v, A[kt][0].v, acc1, 0, 0, 0);
            acc3 = __builtin_amdgcn_mfma_f32_16x16x32_bf16(Wf[3][kt][0].v, A[kt][1].v, acc3, 0, 0, 0);
            acc0 = __builtin_amdgcn_mfma_f32_16x16x32_bf16(Wf[0][kt][0].v, A[kt][1].v, acc0, 0, 0, 0);
            acc2 = __builtin_amdgcn_mfma_f32_16x16x32_bf16(Wf[2][kt][0].v, A[kt][1].v, acc2, 0, 0, 0);
            acc1 = __builtin_amdgcn_mfma_f32_16x16x32_bf16(Wf[1][kt][0].v, A[kt][1].v, acc1, 0, 0, 0);
            acc3 = __builtin_amdgcn_mfma_f32_16x16x32_bf16(Wf[3][kt][1].v, A[kt][0].v, acc3, 0, 0, 0);
            acc0 = __builtin_amdgcn_mfma_f32_16x16x32_bf16(Wf[0][kt][1].v, A[kt][0].v, acc0, 0, 0, 0);
            acc2 = __builtin_amdgcn_mfma_f32_16x16x32_bf16(Wf[2][kt][1].v, A[kt][0].v, acc2, 0, 0, 0);
            acc1 = __builtin_amdgcn_mfma_f32_16x16x32_bf16(Wf[1][kt][1].v, A[kt][0].v, acc1, 0, 0, 0);
        }

        // ---- phase C: per-seq scalars once, then 4 units of gates ----
        const float xh = acc3[0] + rb0;           // all acc3 rows identical (bcast A)
        if (w == 0 && g == 0) impbuf[j][tm] = xh;
        const float mv = xmd.y;
        const float xc = mv * xmd.x + (1.0f - mv) * xh;
#pragma unroll
        for (int q = 0; q < 4; ++q) {
            const float an = wxn[q] * xc + wmn[q] * mv + binq[q];   // indep of rr
            const float bn = acc2[q] + bhnq[q];                     // indep of rr
            const float rr = fsig(acc0[q] + wxr[q] * xc + wmr[q] * mv + brq[q]);
            const float zz = fsig(acc1[q] + wxz[q] * xc + wmz[q] * mv + bzq[q]);
            const float nn = ftanh(an + rr * bn);
            h[q] = (1.0f - zz) * nn + zz * h[q];
        }
    }

    // epilogue: flush last imp chunk + fc reduction
    __syncthreads();
    {
        const int fs = tid >> 4, ft = tid & 15;
        impOut[fs * NT + (NT - 16) + ft] = impbuf[fs][ft];
    }
    float pfc = h[0] * fcq[0] + h[1] * fcq[1] + h[2] * fcq[2] + h[3] * fcq[3];
    pfc += __shfl_xor(pfc, 16);
    pfc += __shfl_xor(pfc, 32);
    if (lane < 16) fcpart[j][w] = pfc;
    __syncthreads();
    if (tid < 16) {
        float4 xp = *(const float4*)&fcpart[tid][0];
        ws[dir * 2048 + b0 + tid] = xp.x + xp.y + xp.z + xp.w + fcb[0];
    }
}

__global__ void brits_combine(const float* __restrict__ ws, float* __restrict__ out)
{
    int i = blockIdx.x * 256 + threadIdx.x;
    if (i < 2048) out[i] = 0.5f * (ws[i] + ws[2048 + i]);
}

extern "C" void kernel_launch(void* const* d_in, const int* in_sizes, int n_in,
                              void* d_out, int out_size, void* d_ws, size_t ws_size,
                              hipStream_t stream)
{
    const float* p[21];
    for (int i = 0; i < 21; ++i) p[i] = (const float*)d_in[i];
    float* out = (float*)d_out;
    float* ws  = (float*)d_ws;   // 4096 floats used

    brits_mfma<<<256, 256, 0, stream>>>(
        p[0],
        p[1], p[2], p[3], p[4], p[5], p[6], p[7], p[8], p[9], p[10],
        p[11], p[12], p[13], p[14], p[15], p[16], p[17], p[18], p[19], p[20],
        out, ws);
    brits_combine<<<8, 256, 0, stream>>>(ws, out);
}